// Round 3
// baseline (2869.997 us; speedup 1.0000x reference)
//
#include <hip/hip_runtime.h>
#include <cstdint>

#define HID 250
#define NIN 128
#define BATCH 512
#define N1 (BATCH * HID)          // 128000 layer-1/2 neuron-chains
#define T_TOTAL 1000
#define OUT_HALF 1024000          // 1000*512*2 floats per output tensor

typedef float f32x2 __attribute__((ext_vector_type(2)));

// ---------------------------------------------------------------------------
// pad_w: one-time prep. W1p[128][256], W2p[250][256] — column-padded copies
// (cols 250..255 zero) for branch-free 16B-aligned float4 loads.
// ---------------------------------------------------------------------------
__global__ __launch_bounds__(256) void pad_w(
    const float* __restrict__ W1, const float* __restrict__ W2,
    float* __restrict__ W1p, float* __restrict__ W2p)
{
    const int i = blockIdx.x * 256 + threadIdx.x;   // grid 250*256 = 64000
    if (i < 128 * 256) {
        const int k = i >> 8, c = i & 255;
        W1p[i] = (c < HID) ? W1[k * HID + c] : 0.0f;
    }
    if (i < 250 * 256) {
        const int k = i >> 8, c = i & 255;
        W2p[i] = (c < HID) ? W2[k * HID + c] : 0.0f;
    }
}

// ---------------------------------------------------------------------------
// GEMM1 v4 (unchanged from round 2).
// ---------------------------------------------------------------------------
__global__ __launch_bounds__(256, 2) void gemm1_v4(
    const float* __restrict__ x,    // [M][128]
    const float* __restrict__ W1p,  // [128][256] padded
    const float* __restrict__ b1,   // [250]
    float* __restrict__ cur,        // [M][250]
    int M)
{
#pragma clang fp contract(off)
    __shared__ __align__(16) float xT[128 * 132];   // 67584 B -> 2 blocks/CU
    const int tid  = threadIdx.x;
    const int lane = tid & 63, wave = tid >> 6;
    const long rowBase = (long)blockIdx.x * 128;

    const float* xb = x + rowBase * NIN;
    #pragma unroll
    for (int i = 0; i < 16; ++i) {
        const int rr  = i & 1;
        const int kq  = (i >> 1) * 4 + wave;
        const int row = rr * 64 + lane;
        const float4 v = *(const float4*)(xb + (long)row * NIN + kq * 4);
        xT[(4 * kq + 0) * 132 + row] = v.x;
        xT[(4 * kq + 1) * 132 + row] = v.y;
        xT[(4 * kq + 2) * 132 + row] = v.z;
        xT[(4 * kq + 3) * 132 + row] = v.w;
    }
    __syncthreads();

    const int ri = tid >> 4;
    const int ci = tid & 15;

    float acc[8][16];
    #pragma unroll
    for (int r = 0; r < 8; ++r)
        #pragma unroll
        for (int c = 0; c < 16; ++c) acc[r][c] = 0.0f;

    #pragma unroll 2
    for (int k = 0; k < NIN; ++k) {
        const float4 a0 = *(const float4*)&xT[k * 132 + 8 * ri];
        const float4 a1 = *(const float4*)&xT[k * 132 + 8 * ri + 4];
        const float* wr = W1p + (k << 8) + 4 * ci;
        const float4 wv0 = *(const float4*)(wr);
        const float4 wv1 = *(const float4*)(wr + 64);
        const float4 wv2 = *(const float4*)(wr + 128);
        const float4 wv3 = *(const float4*)(wr + 192);
        const float w[16] = {wv0.x, wv0.y, wv0.z, wv0.w,
                             wv1.x, wv1.y, wv1.z, wv1.w,
                             wv2.x, wv2.y, wv2.z, wv2.w,
                             wv3.x, wv3.y, wv3.z, wv3.w};
        const float av[8] = {a0.x, a0.y, a0.z, a0.w, a1.x, a1.y, a1.z, a1.w};
        #pragma unroll
        for (int r = 0; r < 8; ++r)
            #pragma unroll
            for (int c = 0; c < 16; ++c)
                acc[r][c] = __builtin_fmaf(av[r], w[c], acc[r][c]);
    }

    #pragma unroll
    for (int j = 0; j < 4; ++j) {
        #pragma unroll
        for (int p = 0; p < 2; ++p) {
            const int cp = 64 * j + 4 * ci + 2 * p;
            if (cp < HID) {
                const float b0 = b1[cp], b1v = b1[cp + 1];
                #pragma unroll
                for (int r = 0; r < 8; ++r) {
                    const long row = rowBase + 8 * ri + r;
                    float2 o;
                    o.x = acc[r][4*j + 2*p]     + b0;
                    o.y = acc[r][4*j + 2*p + 1] + b1v;
                    *(float2*)(cur + row * HID + cp) = o;
                }
            }
        }
    }
}

// ---------------------------------------------------------------------------
// LIF scan layers 1/2 (unchanged).
// ---------------------------------------------------------------------------
__global__ __launch_bounds__(256) void scan_f32(
    const float* __restrict__ cur,   // [Tc][N1]
    uint8_t* __restrict__ spk,       // [Tc][N1]
    float* __restrict__ state,       // [N1]
    int Tc)
{
#pragma clang fp contract(off)
    const int n = blockIdx.x * 256 + threadIdx.x;
    float m = state[n];
    int t = 0;
    for (; t + 8 <= Tc; t += 8) {
        const long base = (long)t * N1 + n;
        float c[8];
        #pragma unroll
        for (int u = 0; u < 8; ++u) c[u] = cur[base + (long)u * N1];
        #pragma unroll
        for (int u = 0; u < 8; ++u) {
            const float r = (m > 1.0f) ? 1.0f : 0.0f;
            float tmp = 0.9f * m; tmp = tmp + c[u]; m = tmp - r;
            spk[base + (long)u * N1] = (m > 1.0f) ? (uint8_t)1 : (uint8_t)0;
        }
    }
    for (; t < Tc; ++t) {
        const long base = (long)t * N1 + n;
        const float c = cur[base];
        const float r = (m > 1.0f) ? 1.0f : 0.0f;
        float tmp = 0.9f * m; tmp = tmp + c; m = tmp - r;
        spk[base] = (m > 1.0f) ? (uint8_t)1 : (uint8_t)0;
    }
    state[n] = m;
}

// ---------------------------------------------------------------------------
// GEMM2 v5: packed-FMA dense-over-k. Block = 512 thr (8 waves), handles 512
// rows x one 64-col chunk (q = blockIdx&3). W2 chunk [250][64] staged in LDS
// via global_load_lds (64 KB). Each wave: 8 groups x 8 rows; per group it
// builds an LDS table s_tab[k][rowpair] of packed (s_2p, s_2p+1) f32 pairs
// (stride 48 B per k to spread write banks ~8-way; reads are broadcast=free),
// then an unrolled k-loop: per k one ds_read_b32 of w (2-way, free), one dup,
// 4 broadcast ds_read_b64 of s-pairs, 4 v_pk_fma_f32 -> 8 rows x 64 cols in
// ~15 issue-cycles (~1.9 cyc/row vs ~8 for the cndmask walk).
// Numerics: acc = fma(s,w,acc) with s in {0.0,1.0}: s=1 -> RN(acc+w) exactly
// the member add; s=0 -> acc unchanged (exact, acc never -0). Single
// accumulator, ascending k, bias added once at the end — bit-identical chain.
// ---------------------------------------------------------------------------
__global__ __launch_bounds__(512, 1) void gemm2_v5(
    const uint8_t* __restrict__ s,   // [M][250] spikes 0/1
    const float* __restrict__ W2p,   // [250][256] padded
    const float* __restrict__ b2,    // [250]
    float* __restrict__ cur,         // [M][250]
    int M)
{
#pragma clang fp contract(off)
    // LDS: Wq 250*64*4 = 64000 B ; s_tab 8 waves * 250*48 = 96000 B ; total 160000
    __shared__ __align__(16) float Wq[250 * 64];
    __shared__ __align__(16) float stab[8 * 250 * 12];   // [wave][k][12 words]
    const int tid  = threadIdx.x;
    const int lane = tid & 63, wave = tid >> 6;
    const int q    = blockIdx.x & 3;                     // cols 64q..64q+63
    const long rb  = (long)(blockIdx.x >> 2) * 512;

    // ---- stage W chunk: 4000 x 16B via global_load_lds (linear dest) ----
    {
        const float* src = W2p + q * 64;                 // [k][256] view
        #pragma unroll
        for (int i = 0; i < 8; ++i) {
            const int idx = i * 512 + tid;               // 0..4095
            if (idx < 4000) {
                const int k = idx >> 4, c4 = (idx & 15) * 4;
                __builtin_amdgcn_global_load_lds(
                    (const __attribute__((address_space(1))) uint32_t*)(src + k * 256 + c4),
                    (__attribute__((address_space(3))) uint32_t*)&Wq[idx * 4],
                    16, 0, 0);
            }
        }
    }
    const int col = q * 64 + lane;
    const float bb = (col < HID) ? b2[col] : 0.0f;
    __syncthreads();

    float* stw = stab + wave * (250 * 12);               // this wave's table
    const float* wq_l = Wq + lane;
    // per-lane s_tab write base: k = 64c + lane -> word 12k + 2p
    float* stw_l = stw + lane * 12;

    for (int g = 0; g < 8; ++g) {
        const long grow = rb + (long)wave * 64 + g * 8;  // 8 consecutive rows
        const uint8_t* sp = s + grow * HID;

        // ---- build s_tab: pairs (row 2p, 2p+1) as packed f32x2 per k ----
        #pragma unroll
        for (int c = 0; c < 4; ++c) {
            uint32_t by[8];
            #pragma unroll
            for (int r = 0; r < 8; ++r)
                by[r] = sp[r * HID + c * 64 + lane];
            if (c < 3 || lane < 58) {                    // k = 64c+lane < 250
                #pragma unroll
                for (int p = 0; p < 4; ++p) {
                    f32x2 sv;
                    sv.x = (float)by[2 * p];
                    sv.y = (float)by[2 * p + 1];
                    *(f32x2*)(stw_l + c * 768 + 2 * p) = sv;  // word 12k+2p
                }
            }
        }
        // same-wave ds_write -> ds_read ordering handled by compiler lgkmcnt

        // ---- inner: dense k, 4 packed row-pair accumulators ----
        f32x2 a0 = {0.0f, 0.0f}, a1 = {0.0f, 0.0f};
        f32x2 a2 = {0.0f, 0.0f}, a3 = {0.0f, 0.0f};
        const f32x2* st2 = (const f32x2*)stw;            // k*6 + p
        #pragma unroll 50
        for (int k = 0; k < HID; ++k) {
            const float w = wq_l[k * 64];
            f32x2 wd; wd.x = w; wd.y = w;
            const f32x2 s0 = st2[k * 6 + 0];
            const f32x2 s1 = st2[k * 6 + 1];
            const f32x2 s2 = st2[k * 6 + 2];
            const f32x2 s3 = st2[k * 6 + 3];
            asm("v_pk_fma_f32 %0, %1, %2, %0" : "+v"(a0) : "v"(s0), "v"(wd));
            asm("v_pk_fma_f32 %0, %1, %2, %0" : "+v"(a1) : "v"(s1), "v"(wd));
            asm("v_pk_fma_f32 %0, %1, %2, %0" : "+v"(a2) : "v"(s2), "v"(wd));
            asm("v_pk_fma_f32 %0, %1, %2, %0" : "+v"(a3) : "v"(s3), "v"(wd));
        }

        // ---- store 8 rows (bias added once, same rounding as before) ----
        if (col < HID) {
            float* cp = cur + grow * HID + col;
            cp[0 * HID] = a0.x + bb;  cp[1 * HID] = a0.y + bb;
            cp[2 * HID] = a1.x + bb;  cp[3 * HID] = a1.y + bb;
            cp[4 * HID] = a2.x + bb;  cp[5 * HID] = a2.y + bb;
            cp[6 * HID] = a3.x + bb;  cp[7 * HID] = a3.y + bb;
        }
    }
}

// ---------------------------------------------------------------------------
// GEMM3 (unchanged).
// ---------------------------------------------------------------------------
__global__ __launch_bounds__(256) void gemm3_f32(
    const uint8_t* __restrict__ s,   // [M][250]
    const float* __restrict__ W3,    // [250][2]
    const float* __restrict__ b3,    // [2]
    float* __restrict__ cur3,        // [M][2]
    int M)
{
#pragma clang fp contract(off)
    __shared__ int wl[4][256];
    const int tid = threadIdx.x;
    const int wave = tid >> 6, lane = tid & 63;
    const long row = (long)blockIdx.x * 4 + wave;

    int base = 0;
    #pragma unroll
    for (int c = 0; c < 4; ++c) {
        const int k = c * 64 + lane;
        const bool sp = (k < HID) && s[row * HID + k];
        unsigned long long mask = __ballot(sp);
        if (sp) wl[wave][base + __popcll(mask & ((1ull << lane) - 1ull))] = k;
        base += __popcll(mask);      // wave-uniform
    }
    __syncthreads();

    if (lane < 2) {
        const int nact = base;
        float acc = 0.0f;
        for (int j = 0; j < nact; ++j)
            acc = acc + W3[wl[wave][j] * 2 + lane];
        cur3[row * 2 + lane] = acc + b3[lane];
    }
}

// ---------------------------------------------------------------------------
// Output scan (unchanged from round 2).
// ---------------------------------------------------------------------------
__global__ __launch_bounds__(256) void scan3_f32(
    const float* __restrict__ cur3,  // [Tc][1024]
    float* __restrict__ state,       // [1024]
    float* __restrict__ out,         // spikes @0, mem @OUT_HALF
    int t0, int Tc)
{
#pragma clang fp contract(off)
    const int n = blockIdx.x * 256 + threadIdx.x;
    float m = state[n];
    int t = 0;
    for (; t + 8 <= Tc; t += 8) {
        float c[8];
        #pragma unroll
        for (int u = 0; u < 8; ++u) c[u] = cur3[(long)(t + u) * 1024 + n];
        #pragma unroll
        for (int u = 0; u < 8; ++u) {
            const float reset = (m > 1.0f) ? 1.0f : 0.0f;
            float tmp = 0.9f * m; tmp = tmp + c[u]; m = tmp - reset;
            const long o = (long)(t0 + t + u) * 1024 + n;
            out[o] = (m > 1.0f) ? 1.0f : 0.0f;
            out[OUT_HALF + o] = m;
        }
    }
    for (; t < Tc; ++t) {
        const float c = cur3[(long)t * 1024 + n];
        const float reset = (m > 1.0f) ? 1.0f : 0.0f;
        float tmp = 0.9f * m; tmp = tmp + c; m = tmp - reset;
        const long o = (long)(t0 + t) * 1024 + n;
        out[o] = (m > 1.0f) ? 1.0f : 0.0f;
        out[OUT_HALF + o] = m;
    }
    state[n] = m;
}

// ---------------------------------------------------------------------------
extern "C" void kernel_launch(void* const* d_in, const int* in_sizes, int n_in,
                              void* d_out, int out_size, void* d_ws, size_t ws_size,
                              hipStream_t stream) {
    const float* x  = (const float*)d_in[0];
    const float* W1 = (const float*)d_in[1];
    const float* b1 = (const float*)d_in[2];
    const float* W2 = (const float*)d_in[3];
    const float* b2 = (const float*)d_in[4];
    const float* W3 = (const float*)d_in[5];
    const float* b3 = (const float*)d_in[6];
    float* out = (float*)d_out;

    char* w = (char*)d_ws;
    size_t off = 0;
    auto alloc = [&](size_t bytes) -> void* {
        void* p = (void*)(w + off);
        off = (off + bytes + 255) & ~(size_t)255;
        return p;
    };

    float* m1 = (float*)alloc((size_t)N1 * 4);      // 512,000 B
    float* m2 = (float*)alloc((size_t)N1 * 4);      // 512,000 B
    float* m3 = (float*)alloc(1024 * 4);            // 4,096 B
    const size_t states = off;                       // zeroed each call
    float* W1p = (float*)alloc(128 * 256 * 4);      // 131,072 B
    float* W2p = (float*)alloc(250 * 256 * 4);      // 256,000 B
    const size_t fixed = off;

    // chunk size from workspace: per-step = cur3(4K) + sbuf(125K) + cur(500K)
    const size_t perT = 4096 + 128000 + 512000;
    long tc_budget = ((long)ws_size - (long)fixed - 4096) / (long)perT;
    int Tc = (int)(tc_budget < 1 ? 1 : (tc_budget > T_TOTAL ? T_TOTAL : tc_budget));

    float*   cur3 = (float*)alloc((size_t)Tc * 4096);
    uint8_t* sbuf = (uint8_t*)alloc((size_t)Tc * 128000);
    float*   cur  = (float*)alloc((size_t)Tc * 512000);

    hipMemsetAsync(d_ws, 0, states, stream);   // zero membrane states
    pad_w<<<250, 256, 0, stream>>>(W1, W2, W1p, W2p);

    for (int t0 = 0; t0 < T_TOTAL; t0 += Tc) {
        const int tc = (T_TOTAL - t0 < Tc) ? (T_TOTAL - t0) : Tc;
        const int M = tc * BATCH;   // divisible by 512

        gemm1_v4<<<M / 128, 256, 0, stream>>>(x + (size_t)t0 * BATCH * NIN,
                                              W1p, b1, cur, M);
        scan_f32<<<N1 / 256, 256, 0, stream>>>(cur, sbuf, m1, tc);
        gemm2_v5<<<(M / 512) * 4, 512, 0, stream>>>(sbuf, W2p, b2, cur, M);
        scan_f32<<<N1 / 256, 256, 0, stream>>>(cur, sbuf, m2, tc);
        gemm3_f32<<<M / 4, 256, 0, stream>>>(sbuf, W3, b3, cur3, M);
        scan3_f32<<<4, 256, 0, stream>>>(cur3, m3, out, t0, tc);
    }
}

// Round 4
// 2277.126 us; speedup vs baseline: 1.2604x; 1.2604x over previous
//
#include <hip/hip_runtime.h>
#include <cstdint>

#define HID 250
#define NIN 128
#define BATCH 512
#define N1 (BATCH * HID)          // 128000 layer-1/2 neuron-chains
#define T_TOTAL 1000
#define OUT_HALF 1024000          // 1000*512*2 floats per output tensor

// ---------------------------------------------------------------------------
// pad_w: one-time prep. W1p[129][256] (row 128 = zeros, guard-free k+1
// prefetch), W2p[250][256] — column-padded copies (cols 250..255 zero) for
// branch-free 16B-aligned float4 loads.
// ---------------------------------------------------------------------------
__global__ __launch_bounds__(256) void pad_w(
    const float* __restrict__ W1, const float* __restrict__ W2,
    float* __restrict__ W1p, float* __restrict__ W2p)
{
    const int i = blockIdx.x * 256 + threadIdx.x;   // grid 258 blocks
    if (i < 129 * 256) {
        const int k = i >> 8, c = i & 255;
        W1p[i] = (k < NIN && c < HID) ? W1[k * HID + c] : 0.0f;
    }
    if (i < 250 * 256) {
        const int k = i >> 8, c = i & 255;
        W2p[i] = (c < HID) ? W2[k * HID + c] : 0.0f;
    }
}

// ---------------------------------------------------------------------------
// GEMM1 v5: 64 rows x 256 cols per block (256 thr), 34.8 KB LDS -> 4
// blocks/CU (50% occ). Inner k-loop software-pipelined 1 deep on the W row
// (the L2-latency loads): W1p padded to 129 rows so the k+1 prefetch is
// guard-free; unroll 2 so the rotation is register-renamed. Per k: 4 W
// float4 prefetches + 1 LDS broadcast a-read + 64 FMAs (~132 cyc of cover
// per wave, x4 waves/SIMD TLP).
// Numerics: per output element single accumulator, fused fmaf, k ascending —
// bit-identical chain to v2/v4.
// ---------------------------------------------------------------------------
__global__ __launch_bounds__(256, 4) void gemm1_v5(
    const float* __restrict__ x,    // [M][128]
    const float* __restrict__ W1p,  // [129][256] padded
    const float* __restrict__ b1,   // [250]
    float* __restrict__ cur,        // [M][250]
    int M)
{
#pragma clang fp contract(off)
    __shared__ __align__(16) float xT[128 * 68];   // 34816 B
    const int tid  = threadIdx.x;
    const int lane = tid & 63, wave = tid >> 6;
    const long rowBase = (long)blockIdx.x * 64;

    // stage x[rowBase..+64][0..128) transposed; LDS writes conflict-free
    const float* xb = x + rowBase * NIN;
    #pragma unroll
    for (int i = 0; i < 8; ++i) {
        const int kq = i * 4 + wave;
        const float4 v = *(const float4*)(xb + (long)lane * NIN + kq * 4);
        xT[(4 * kq + 0) * 68 + lane] = v.x;
        xT[(4 * kq + 1) * 68 + lane] = v.y;
        xT[(4 * kq + 2) * 68 + lane] = v.z;
        xT[(4 * kq + 3) * 68 + lane] = v.w;
    }
    __syncthreads();

    const int ri = tid >> 4;   // 0..15 -> rows 4ri..4ri+3
    const int ci = tid & 15;   // 0..15 -> col quads 64j + 4ci

    float acc[4][16];
    #pragma unroll
    for (int r = 0; r < 4; ++r)
        #pragma unroll
        for (int c = 0; c < 16; ++c) acc[r][c] = 0.0f;

    // k=0 W row preload
    const float* wp = W1p + 4 * ci;
    float4 cw0 = *(const float4*)(wp);
    float4 cw1 = *(const float4*)(wp + 64);
    float4 cw2 = *(const float4*)(wp + 128);
    float4 cw3 = *(const float4*)(wp + 192);
    const float* xp = xT + 4 * ri;

    #pragma unroll 2
    for (int k = 0; k < NIN; ++k) {
        // prefetch k+1 (row 128 = zero pad, never used in FMA)
        wp += 256;
        const float4 n0 = *(const float4*)(wp);
        const float4 n1 = *(const float4*)(wp + 64);
        const float4 n2 = *(const float4*)(wp + 128);
        const float4 n3 = *(const float4*)(wp + 192);
        const float4 a  = *(const float4*)(xp);
        xp += 68;
        const float w[16] = {cw0.x, cw0.y, cw0.z, cw0.w,
                             cw1.x, cw1.y, cw1.z, cw1.w,
                             cw2.x, cw2.y, cw2.z, cw2.w,
                             cw3.x, cw3.y, cw3.z, cw3.w};
        const float av[4] = {a.x, a.y, a.z, a.w};
        #pragma unroll
        for (int r = 0; r < 4; ++r)
            #pragma unroll
            for (int c = 0; c < 16; ++c)
                acc[r][c] = __builtin_fmaf(av[r], w[c], acc[r][c]);
        cw0 = n0; cw1 = n1; cw2 = n2; cw3 = n3;
    }

    // epilogue: +bias (separately rounded), float2 stores (250 even -> 8B ok)
    #pragma unroll
    for (int j = 0; j < 4; ++j) {
        #pragma unroll
        for (int p = 0; p < 2; ++p) {
            const int cp = 64 * j + 4 * ci + 2 * p;
            if (cp < HID) {
                const float b0 = b1[cp], b1v = b1[cp + 1];
                #pragma unroll
                for (int r = 0; r < 4; ++r) {
                    const long row = rowBase + 4 * ri + r;
                    float2 o;
                    o.x = acc[r][4*j + 2*p]     + b0;
                    o.y = acc[r][4*j + 2*p + 1] + b1v;
                    *(float2*)(cur + row * HID + cp) = o;
                }
            }
        }
    }
}

// ---------------------------------------------------------------------------
// LIF scan layers 1/2 (unchanged): unroll x8, loads batched ahead.
// ---------------------------------------------------------------------------
__global__ __launch_bounds__(256) void scan_f32(
    const float* __restrict__ cur,   // [Tc][N1]
    uint8_t* __restrict__ spk,       // [Tc][N1]
    float* __restrict__ state,       // [N1]
    int Tc)
{
#pragma clang fp contract(off)
    const int n = blockIdx.x * 256 + threadIdx.x;
    float m = state[n];
    int t = 0;
    for (; t + 8 <= Tc; t += 8) {
        const long base = (long)t * N1 + n;
        float c[8];
        #pragma unroll
        for (int u = 0; u < 8; ++u) c[u] = cur[base + (long)u * N1];
        #pragma unroll
        for (int u = 0; u < 8; ++u) {
            const float r = (m > 1.0f) ? 1.0f : 0.0f;
            float tmp = 0.9f * m; tmp = tmp + c[u]; m = tmp - r;
            spk[base + (long)u * N1] = (m > 1.0f) ? (uint8_t)1 : (uint8_t)0;
        }
    }
    for (; t < Tc; ++t) {
        const long base = (long)t * N1 + n;
        const float c = cur[base];
        const float r = (m > 1.0f) ? 1.0f : 0.0f;
        float tmp = 0.9f * m; tmp = tmp + c; m = tmp - r;
        spk[base] = (m > 1.0f) ? (uint8_t)1 : (uint8_t)0;
    }
    state[n] = m;
}

// ---------------------------------------------------------------------------
// GEMM2 v4 (reverted to round-2 version — measured 885 us, VALU-issue-bound
// near its structural floor): 32-col LDS chunk, 2 rows per wave, union-mask
// ctz walk with cndmask-add. Numerics bit-identical (ascending-k member adds;
// +0.0f identity for non-members).
// ---------------------------------------------------------------------------
__global__ __launch_bounds__(512, 4) void gemm2_v4(
    const uint8_t* __restrict__ s,   // [M][250] spikes 0/1
    const float* __restrict__ W2p,   // [250][256] padded
    const float* __restrict__ b2,    // [250]
    float* __restrict__ cur,         // [M][250]
    int M)
{
#pragma clang fp contract(off)
    __shared__ __align__(16) float Wq[250 * 32];   // 32000 B
    const int tid  = threadIdx.x;
    const int lane = tid & 63, wave = tid >> 6;    // wave 0..7
    const int q    = blockIdx.x & 7;               // cols 32q..32q+31
    const long r0  = (long)(blockIdx.x >> 3) * 128;
    const int c32  = lane & 31;
    const int half = lane >> 5;                    // 0 -> row a, 1 -> row b

    // stage chunk: Wq[k][c] = W2p[k][32q + c]; 2000 float4s over 512 thr
    {
        const float* src = W2p + q * 32;
        #pragma unroll
        for (int i = 0; i < 4; ++i) {
            const int idx = i * 512 + tid;         // 0..2047
            if (idx < 2000) {
                const int k = idx >> 3, c4 = (idx & 7) * 4;
                *(float4*)&Wq[k * 32 + c4] = *(const float4*)(src + k * 256 + c4);
            }
        }
    }
    const int col = q * 32 + c32;
    const float bb = (col < HID) ? b2[col] : 0.0f;
    __syncthreads();

    // 8 row-pairs per wave: block covers rows r0 .. r0+127
    for (int p = 0; p < 8; ++p) {
        const long ra = r0 + wave * 16 + 2 * p;
        const long rb = ra + 1;
        const uint8_t* pa = s + ra * HID;
        const uint8_t* pb = s + rb * HID;
        unsigned long long ma[4], mb[4];
        #pragma unroll
        for (int c = 0; c < 4; ++c) {
            const int k = c * 64 + lane;
            ma[c] = __ballot((k < HID) && pa[k]);
            mb[c] = __ballot((k < HID) && pb[k]);
        }
        float acc = 0.0f;
        #pragma unroll
        for (int c = 0; c < 4; ++c) {
            unsigned long long mu = ma[c] | mb[c];          // uniform
            const unsigned long long msel = half ? mb[c] : ma[c];
            while (mu) {
                const int k = __builtin_ctzll(mu);
                mu &= mu - 1;
                const float wv = Wq[(c * 64 + k) * 32 + c32];
                acc = acc + (((msel >> k) & 1ull) ? wv : 0.0f);
            }
        }
        const long row = half ? rb : ra;
        if (col < HID) cur[row * HID + col] = acc + bb;
    }
}

// ---------------------------------------------------------------------------
// GEMM3 (unchanged).
// ---------------------------------------------------------------------------
__global__ __launch_bounds__(256) void gemm3_f32(
    const uint8_t* __restrict__ s,   // [M][250]
    const float* __restrict__ W3,    // [250][2]
    const float* __restrict__ b3,    // [2]
    float* __restrict__ cur3,        // [M][2]
    int M)
{
#pragma clang fp contract(off)
    __shared__ int wl[4][256];
    const int tid = threadIdx.x;
    const int wave = tid >> 6, lane = tid & 63;
    const long row = (long)blockIdx.x * 4 + wave;

    int base = 0;
    #pragma unroll
    for (int c = 0; c < 4; ++c) {
        const int k = c * 64 + lane;
        const bool sp = (k < HID) && s[row * HID + k];
        unsigned long long mask = __ballot(sp);
        if (sp) wl[wave][base + __popcll(mask & ((1ull << lane) - 1ull))] = k;
        base += __popcll(mask);      // wave-uniform
    }
    __syncthreads();

    if (lane < 2) {
        const int nact = base;
        float acc = 0.0f;
        for (int j = 0; j < nact; ++j)
            acc = acc + W3[wl[wave][j] * 2 + lane];
        cur3[row * 2 + lane] = acc + b3[lane];
    }
}

// ---------------------------------------------------------------------------
// Output scan (unchanged): batch-8 loads ahead of the dependent recurrence.
// ---------------------------------------------------------------------------
__global__ __launch_bounds__(256) void scan3_f32(
    const float* __restrict__ cur3,  // [Tc][1024]
    float* __restrict__ state,       // [1024]
    float* __restrict__ out,         // spikes @0, mem @OUT_HALF
    int t0, int Tc)
{
#pragma clang fp contract(off)
    const int n = blockIdx.x * 256 + threadIdx.x;
    float m = state[n];
    int t = 0;
    for (; t + 8 <= Tc; t += 8) {
        float c[8];
        #pragma unroll
        for (int u = 0; u < 8; ++u) c[u] = cur3[(long)(t + u) * 1024 + n];
        #pragma unroll
        for (int u = 0; u < 8; ++u) {
            const float reset = (m > 1.0f) ? 1.0f : 0.0f;
            float tmp = 0.9f * m; tmp = tmp + c[u]; m = tmp - reset;
            const long o = (long)(t0 + t + u) * 1024 + n;
            out[o] = (m > 1.0f) ? 1.0f : 0.0f;
            out[OUT_HALF + o] = m;
        }
    }
    for (; t < Tc; ++t) {
        const float c = cur3[(long)t * 1024 + n];
        const float reset = (m > 1.0f) ? 1.0f : 0.0f;
        float tmp = 0.9f * m; tmp = tmp + c; m = tmp - reset;
        const long o = (long)(t0 + t) * 1024 + n;
        out[o] = (m > 1.0f) ? 1.0f : 0.0f;
        out[OUT_HALF + o] = m;
    }
    state[n] = m;
}

// ---------------------------------------------------------------------------
extern "C" void kernel_launch(void* const* d_in, const int* in_sizes, int n_in,
                              void* d_out, int out_size, void* d_ws, size_t ws_size,
                              hipStream_t stream) {
    const float* x  = (const float*)d_in[0];
    const float* W1 = (const float*)d_in[1];
    const float* b1 = (const float*)d_in[2];
    const float* W2 = (const float*)d_in[3];
    const float* b2 = (const float*)d_in[4];
    const float* W3 = (const float*)d_in[5];
    const float* b3 = (const float*)d_in[6];
    float* out = (float*)d_out;

    char* w = (char*)d_ws;
    size_t off = 0;
    auto alloc = [&](size_t bytes) -> void* {
        void* p = (void*)(w + off);
        off = (off + bytes + 255) & ~(size_t)255;
        return p;
    };

    float* m1 = (float*)alloc((size_t)N1 * 4);      // 512,000 B
    float* m2 = (float*)alloc((size_t)N1 * 4);      // 512,000 B
    float* m3 = (float*)alloc(1024 * 4);            // 4,096 B
    const size_t states = off;                       // zeroed each call
    float* W1p = (float*)alloc(129 * 256 * 4);      // 132,096 B (extra zero row)
    float* W2p = (float*)alloc(250 * 256 * 4);      // 256,000 B
    const size_t fixed = off;

    // chunk size from workspace: per-step = cur3(4K) + sbuf(125K) + cur(500K)
    const size_t perT = 4096 + 128000 + 512000;
    long tc_budget = ((long)ws_size - (long)fixed - 4096) / (long)perT;
    int Tc = (int)(tc_budget < 1 ? 1 : (tc_budget > T_TOTAL ? T_TOTAL : tc_budget));

    float*   cur3 = (float*)alloc((size_t)Tc * 4096);
    uint8_t* sbuf = (uint8_t*)alloc((size_t)Tc * 128000);
    float*   cur  = (float*)alloc((size_t)Tc * 512000);

    hipMemsetAsync(d_ws, 0, states, stream);   // zero membrane states
    pad_w<<<258, 256, 0, stream>>>(W1, W2, W1p, W2p);

    for (int t0 = 0; t0 < T_TOTAL; t0 += Tc) {
        const int tc = (T_TOTAL - t0 < Tc) ? (T_TOTAL - t0) : Tc;
        const int M = tc * BATCH;   // divisible by 512

        gemm1_v5<<<M / 64, 256, 0, stream>>>(x + (size_t)t0 * BATCH * NIN,
                                             W1p, b1, cur, M);
        scan_f32<<<N1 / 256, 256, 0, stream>>>(cur, sbuf, m1, tc);
        gemm2_v4<<<(M / 128) * 8, 512, 0, stream>>>(sbuf, W2p, b2, cur, M);
        scan_f32<<<N1 / 256, 256, 0, stream>>>(cur, sbuf, m2, tc);
        gemm3_f32<<<M / 4, 256, 0, stream>>>(sbuf, W3, b3, cur3, M);
        scan3_f32<<<4, 256, 0, stream>>>(cur3, m3, out, t0, tc);
    }
}

// Round 5
// 2134.418 us; speedup vs baseline: 1.3446x; 1.0669x over previous
//
#include <hip/hip_runtime.h>
#include <cstdint>

#define HID 250
#define NIN 128
#define BATCH 512
#define N1 (BATCH * HID)          // 128000 layer-1/2 neuron-chains
#define T_TOTAL 1000
#define OUT_HALF 1024000          // 1000*512*2 floats per output tensor

// ---------------------------------------------------------------------------
// pad_w: one-time prep. W1p[129][256] (row 128 zeros), W2p[250][256] —
// column-padded copies (cols 250..255 zero) for branch-free 16B float4 loads.
// ---------------------------------------------------------------------------
__global__ __launch_bounds__(256) void pad_w(
    const float* __restrict__ W1, const float* __restrict__ W2,
    float* __restrict__ W1p, float* __restrict__ W2p)
{
    const int i = blockIdx.x * 256 + threadIdx.x;   // grid 258 blocks
    if (i < 129 * 256) {
        const int k = i >> 8, c = i & 255;
        W1p[i] = (k < NIN && c < HID) ? W1[k * HID + c] : 0.0f;
    }
    if (i < 250 * 256) {
        const int k = i >> 8, c = i & 255;
        W2p[i] = (c < HID) ? W2[k * HID + c] : 0.0f;
    }
}

// ---------------------------------------------------------------------------
// GEMM1 v6: 64 rows x 256 cols per block (256 thr). W1 read from LDS:
// per quarter (32 k), stage Wl[32][256] (32 KB) cooperatively, barrier, then
// a pure-LDS inner loop: per k 1 broadcast a-read + 4 ds_read_b128 of W +
// 64 FMAs. No global loads inside the k-loop -> no L2-latency chain (the
// v2/v4/v5 wall). LDS total 67.6 KB -> 2 blocks/CU; barrier drains covered
// by the co-resident block.
// Numerics: k = 32q + kk ascending, single accumulator per output element,
// fused fmaf — chain bit-identical to v2/v4/v5.
// ---------------------------------------------------------------------------
__global__ __launch_bounds__(256, 2) void gemm1_v6(
    const float* __restrict__ x,    // [M][128]
    const float* __restrict__ W1p,  // [129][256] padded
    const float* __restrict__ b1,   // [250]
    float* __restrict__ cur,        // [M][250]
    int M)
{
#pragma clang fp contract(off)
    __shared__ __align__(16) float xT[128 * 68];   // 34816 B
    __shared__ __align__(16) float Wl[32 * 256];   // 32768 B
    const int tid  = threadIdx.x;
    const int lane = tid & 63, wave = tid >> 6;
    const long rowBase = (long)blockIdx.x * 64;

    // stage x[rowBase..+64][0..128) transposed; LDS writes conflict-free
    const float* xb = x + rowBase * NIN;
    #pragma unroll
    for (int i = 0; i < 8; ++i) {
        const int kq = i * 4 + wave;
        const float4 v = *(const float4*)(xb + (long)lane * NIN + kq * 4);
        xT[(4 * kq + 0) * 68 + lane] = v.x;
        xT[(4 * kq + 1) * 68 + lane] = v.y;
        xT[(4 * kq + 2) * 68 + lane] = v.z;
        xT[(4 * kq + 3) * 68 + lane] = v.w;
    }

    const int ri = tid >> 4;   // 0..15 -> rows 4ri..4ri+3
    const int ci = tid & 15;   // 0..15 -> col quads 64j + 4ci

    float acc[4][16];
    #pragma unroll
    for (int r = 0; r < 4; ++r)
        #pragma unroll
        for (int c = 0; c < 16; ++c) acc[r][c] = 0.0f;

    for (int q = 0; q < 4; ++q) {
        __syncthreads();   // q=0: joins xT staging; q>0: Wl reuse guard
        {   // stage W quarter: rows 32q..32q+31 (32 KB), coalesced, 2-way LDS
            const float* src = W1p + q * 32 * 256;
            #pragma unroll
            for (int i = 0; i < 8; ++i) {
                const int u = i * 256 + tid;           // 16B unit 0..2047
                *(float4*)&Wl[u * 4] = *(const float4*)(src + u * 4);
            }
        }
        __syncthreads();

        const float* xp = xT + (q * 32) * 68 + 4 * ri;
        #pragma unroll 4
        for (int kk = 0; kk < 32; ++kk) {
            const float4 a = *(const float4*)(xp);     // broadcast
            xp += 68;
            const float* wr = Wl + kk * 256 + 4 * ci;
            const float4 wv0 = *(const float4*)(wr);
            const float4 wv1 = *(const float4*)(wr + 64);
            const float4 wv2 = *(const float4*)(wr + 128);
            const float4 wv3 = *(const float4*)(wr + 192);
            const float w[16] = {wv0.x, wv0.y, wv0.z, wv0.w,
                                 wv1.x, wv1.y, wv1.z, wv1.w,
                                 wv2.x, wv2.y, wv2.z, wv2.w,
                                 wv3.x, wv3.y, wv3.z, wv3.w};
            const float av[4] = {a.x, a.y, a.z, a.w};
            #pragma unroll
            for (int r = 0; r < 4; ++r)
                #pragma unroll
                for (int c = 0; c < 16; ++c)
                    acc[r][c] = __builtin_fmaf(av[r], w[c], acc[r][c]);
        }
    }

    // epilogue: +bias (separately rounded), float2 stores (250 even -> 8B ok)
    #pragma unroll
    for (int j = 0; j < 4; ++j) {
        #pragma unroll
        for (int p = 0; p < 2; ++p) {
            const int cp = 64 * j + 4 * ci + 2 * p;
            if (cp < HID) {
                const float b0 = b1[cp], b1v = b1[cp + 1];
                #pragma unroll
                for (int r = 0; r < 4; ++r) {
                    const long row = rowBase + 4 * ri + r;
                    float2 o;
                    o.x = acc[r][4*j + 2*p]     + b0;
                    o.y = acc[r][4*j + 2*p + 1] + b1v;
                    *(float2*)(cur + row * HID + cp) = o;
                }
            }
        }
    }
}

// ---------------------------------------------------------------------------
// LIF scan layers 1/2 (unchanged): unroll x8, loads batched ahead.
// ---------------------------------------------------------------------------
__global__ __launch_bounds__(256) void scan_f32(
    const float* __restrict__ cur,   // [Tc][N1]
    uint8_t* __restrict__ spk,       // [Tc][N1]
    float* __restrict__ state,       // [N1]
    int Tc)
{
#pragma clang fp contract(off)
    const int n = blockIdx.x * 256 + threadIdx.x;
    float m = state[n];
    int t = 0;
    for (; t + 8 <= Tc; t += 8) {
        const long base = (long)t * N1 + n;
        float c[8];
        #pragma unroll
        for (int u = 0; u < 8; ++u) c[u] = cur[base + (long)u * N1];
        #pragma unroll
        for (int u = 0; u < 8; ++u) {
            const float r = (m > 1.0f) ? 1.0f : 0.0f;
            float tmp = 0.9f * m; tmp = tmp + c[u]; m = tmp - r;
            spk[base + (long)u * N1] = (m > 1.0f) ? (uint8_t)1 : (uint8_t)0;
        }
    }
    for (; t < Tc; ++t) {
        const long base = (long)t * N1 + n;
        const float c = cur[base];
        const float r = (m > 1.0f) ? 1.0f : 0.0f;
        float tmp = 0.9f * m; tmp = tmp + c; m = tmp - r;
        spk[base] = (m > 1.0f) ? (uint8_t)1 : (uint8_t)0;
    }
    state[n] = m;
}

// ---------------------------------------------------------------------------
// GEMM2 v4 (unchanged — measured 880 us, VALU-issue-bound at ~dense-fp32
// floor; MFMA/bf16 paths rejected on numerics: W2 rounding would flip
// threshold-marginal hidden spikes which cascade to binary outputs).
// ---------------------------------------------------------------------------
__global__ __launch_bounds__(512, 4) void gemm2_v4(
    const uint8_t* __restrict__ s,   // [M][250] spikes 0/1
    const float* __restrict__ W2p,   // [250][256] padded
    const float* __restrict__ b2,    // [250]
    float* __restrict__ cur,         // [M][250]
    int M)
{
#pragma clang fp contract(off)
    __shared__ __align__(16) float Wq[250 * 32];   // 32000 B
    const int tid  = threadIdx.x;
    const int lane = tid & 63, wave = tid >> 6;    // wave 0..7
    const int q    = blockIdx.x & 7;               // cols 32q..32q+31
    const long r0  = (long)(blockIdx.x >> 3) * 128;
    const int c32  = lane & 31;
    const int half = lane >> 5;                    // 0 -> row a, 1 -> row b

    {
        const float* src = W2p + q * 32;
        #pragma unroll
        for (int i = 0; i < 4; ++i) {
            const int idx = i * 512 + tid;         // 0..2047
            if (idx < 2000) {
                const int k = idx >> 3, c4 = (idx & 7) * 4;
                *(float4*)&Wq[k * 32 + c4] = *(const float4*)(src + k * 256 + c4);
            }
        }
    }
    const int col = q * 32 + c32;
    const float bb = (col < HID) ? b2[col] : 0.0f;
    __syncthreads();

    for (int p = 0; p < 8; ++p) {
        const long ra = r0 + wave * 16 + 2 * p;
        const long rb = ra + 1;
        const uint8_t* pa = s + ra * HID;
        const uint8_t* pb = s + rb * HID;
        unsigned long long ma[4], mb[4];
        #pragma unroll
        for (int c = 0; c < 4; ++c) {
            const int k = c * 64 + lane;
            ma[c] = __ballot((k < HID) && pa[k]);
            mb[c] = __ballot((k < HID) && pb[k]);
        }
        float acc = 0.0f;
        #pragma unroll
        for (int c = 0; c < 4; ++c) {
            unsigned long long mu = ma[c] | mb[c];          // uniform
            const unsigned long long msel = half ? mb[c] : ma[c];
            while (mu) {
                const int k = __builtin_ctzll(mu);
                mu &= mu - 1;
                const float wv = Wq[(c * 64 + k) * 32 + c32];
                acc = acc + (((msel >> k) & 1ull) ? wv : 0.0f);
            }
        }
        const long row = half ? rb : ra;
        if (col < HID) cur[row * HID + col] = acc + bb;
    }
}

// ---------------------------------------------------------------------------
// GEMM3 v2: sum loop batches 4 independent W3 loads ahead of 4 in-order adds
// (dependent chain unchanged -> bit-identical; kills the per-iter load wait
// in the 2-active-lane serial sum).
// ---------------------------------------------------------------------------
__global__ __launch_bounds__(256) void gemm3_f32(
    const uint8_t* __restrict__ s,   // [M][250]
    const float* __restrict__ W3,    // [250][2]
    const float* __restrict__ b3,    // [2]
    float* __restrict__ cur3,        // [M][2]
    int M)
{
#pragma clang fp contract(off)
    __shared__ int wl[4][256];
    const int tid = threadIdx.x;
    const int wave = tid >> 6, lane = tid & 63;
    const long row = (long)blockIdx.x * 4 + wave;

    int base = 0;
    #pragma unroll
    for (int c = 0; c < 4; ++c) {
        const int k = c * 64 + lane;
        const bool sp = (k < HID) && s[row * HID + k];
        unsigned long long mask = __ballot(sp);
        if (sp) wl[wave][base + __popcll(mask & ((1ull << lane) - 1ull))] = k;
        base += __popcll(mask);      // wave-uniform
    }
    __syncthreads();

    if (lane < 2) {
        const int nact = base;
        const int* l = wl[wave];
        float acc = 0.0f;
        int j = 0;
        for (; j + 4 <= nact; j += 4) {
            const float w0 = W3[l[j]     * 2 + lane];
            const float w1 = W3[l[j + 1] * 2 + lane];
            const float w2 = W3[l[j + 2] * 2 + lane];
            const float w3 = W3[l[j + 3] * 2 + lane];
            acc = acc + w0; acc = acc + w1; acc = acc + w2; acc = acc + w3;
        }
        for (; j < nact; ++j) acc = acc + W3[l[j] * 2 + lane];
        cur3[row * 2 + lane] = acc + b3[lane];
    }
}

// ---------------------------------------------------------------------------
// Output scan (unchanged): batch-8 loads ahead of the dependent recurrence.
// ---------------------------------------------------------------------------
__global__ __launch_bounds__(256) void scan3_f32(
    const float* __restrict__ cur3,  // [Tc][1024]
    float* __restrict__ state,       // [1024]
    float* __restrict__ out,         // spikes @0, mem @OUT_HALF
    int t0, int Tc)
{
#pragma clang fp contract(off)
    const int n = blockIdx.x * 256 + threadIdx.x;
    float m = state[n];
    int t = 0;
    for (; t + 8 <= Tc; t += 8) {
        float c[8];
        #pragma unroll
        for (int u = 0; u < 8; ++u) c[u] = cur3[(long)(t + u) * 1024 + n];
        #pragma unroll
        for (int u = 0; u < 8; ++u) {
            const float reset = (m > 1.0f) ? 1.0f : 0.0f;
            float tmp = 0.9f * m; tmp = tmp + c[u]; m = tmp - reset;
            const long o = (long)(t0 + t + u) * 1024 + n;
            out[o] = (m > 1.0f) ? 1.0f : 0.0f;
            out[OUT_HALF + o] = m;
        }
    }
    for (; t < Tc; ++t) {
        const float c = cur3[(long)t * 1024 + n];
        const float reset = (m > 1.0f) ? 1.0f : 0.0f;
        float tmp = 0.9f * m; tmp = tmp + c; m = tmp - reset;
        const long o = (long)(t0 + t) * 1024 + n;
        out[o] = (m > 1.0f) ? 1.0f : 0.0f;
        out[OUT_HALF + o] = m;
    }
    state[n] = m;
}

// ---------------------------------------------------------------------------
extern "C" void kernel_launch(void* const* d_in, const int* in_sizes, int n_in,
                              void* d_out, int out_size, void* d_ws, size_t ws_size,
                              hipStream_t stream) {
    const float* x  = (const float*)d_in[0];
    const float* W1 = (const float*)d_in[1];
    const float* b1 = (const float*)d_in[2];
    const float* W2 = (const float*)d_in[3];
    const float* b2 = (const float*)d_in[4];
    const float* W3 = (const float*)d_in[5];
    const float* b3 = (const float*)d_in[6];
    float* out = (float*)d_out;

    char* w = (char*)d_ws;
    size_t off = 0;
    auto alloc = [&](size_t bytes) -> void* {
        void* p = (void*)(w + off);
        off = (off + bytes + 255) & ~(size_t)255;
        return p;
    };

    float* m1 = (float*)alloc((size_t)N1 * 4);      // 512,000 B
    float* m2 = (float*)alloc((size_t)N1 * 4);      // 512,000 B
    float* m3 = (float*)alloc(1024 * 4);            // 4,096 B
    const size_t states = off;                       // zeroed each call
    float* W1p = (float*)alloc(129 * 256 * 4);      // 132,096 B
    float* W2p = (float*)alloc(250 * 256 * 4);      // 256,000 B
    const size_t fixed = off;

    // chunk size from workspace: per-step = cur3(4K) + sbuf(125K) + cur(500K)
    const size_t perT = 4096 + 128000 + 512000;
    long tc_budget = ((long)ws_size - (long)fixed - 4096) / (long)perT;
    int Tc = (int)(tc_budget < 1 ? 1 : (tc_budget > T_TOTAL ? T_TOTAL : tc_budget));

    float*   cur3 = (float*)alloc((size_t)Tc * 4096);
    uint8_t* sbuf = (uint8_t*)alloc((size_t)Tc * 128000);
    float*   cur  = (float*)alloc((size_t)Tc * 512000);

    hipMemsetAsync(d_ws, 0, states, stream);   // zero membrane states
    pad_w<<<258, 256, 0, stream>>>(W1, W2, W1p, W2p);

    for (int t0 = 0; t0 < T_TOTAL; t0 += Tc) {
        const int tc = (T_TOTAL - t0 < Tc) ? (T_TOTAL - t0) : Tc;
        const int M = tc * BATCH;   // divisible by 512

        gemm1_v6<<<M / 64, 256, 0, stream>>>(x + (size_t)t0 * BATCH * NIN,
                                             W1p, b1, cur, M);
        scan_f32<<<N1 / 256, 256, 0, stream>>>(cur, sbuf, m1, tc);
        gemm2_v4<<<(M / 128) * 8, 512, 0, stream>>>(sbuf, W2p, b2, cur, M);
        scan_f32<<<N1 / 256, 256, 0, stream>>>(cur, sbuf, m2, tc);
        gemm3_f32<<<M / 4, 256, 0, stream>>>(sbuf, W3, b3, cur3, M);
        scan3_f32<<<4, 256, 0, stream>>>(cur3, m3, out, t0, tc);
    }
}